// Round 1
// baseline (2805.614 us; speedup 1.0000x reference)
//
#include <hip/hip_runtime.h>
#include <math.h>

// KERNEL_WIDTH = sqrt(9/pi); constants derived in double, stored as f32.
#define KW2_F     2.8647889756541161f   // (9/pi)
#define INV_KW_F  0.5908179502964271f   // 1/sqrt(9/pi)

// Generic tube-of-response projection.
// Permuted-frame axis i corresponds to original image axis a_i.
// img is the ORIGINAL [G0,G1,G2] row-major image; we index it with the
// permuted strides so no transpose is materialized.
__global__ __launch_bounds__(256)
void tor_kernel(const float* __restrict__ img,
                const int*   __restrict__ grid,
                const float* __restrict__ center,
                const float* __restrict__ size,
                const float* __restrict__ lors,
                float*       __restrict__ out,
                int n, int a0, int a1, int a2)
{
    int i = blockIdx.x * blockDim.x + threadIdx.x;
    if (i >= n) return;

    const int G0 = grid[0], G1 = grid[1], G2 = grid[2];

    // dim and stride of an original axis
    auto dimOf    = [&](int a) { return a == 0 ? G0 : (a == 1 ? G1 : G2); };
    auto strideOf = [&](int a) { return a == 0 ? G1 * G2 : (a == 1 ? G2 : 1); };

    const int n0 = dimOf(a0), n1 = dimOf(a1), n2 = dimOf(a2);
    const int s0 = strideOf(a0), s1 = strideOf(a1), s2 = strideOf(a2);

    const float sz0 = size[a0], sz1 = size[a1], sz2 = size[a2];
    const float vs0 = sz0 / (float)n0;
    const float vs1 = sz1 / (float)n1;
    const float vs2 = sz2 / (float)n2;
    const float lo0 = center[a0] - 0.5f * sz0;
    const float lo1 = center[a1] - 0.5f * sz1;
    const float lo2 = center[a2] - 0.5f * sz2;
    const float inv_vs0 = 1.0f / vs0;
    const float inv_vs1 = 1.0f / vs1;

    const float* L = lors + 6 * (size_t)i;
    const float p1x = L[0], p1y = L[1], p1z = L[2];
    const float p2x = L[3], p2y = L[4], p2z = L[5];
    const float dx = p2x - p1x, dy = p2y - p1y, dz = p2z - p1z;
    const float len = sqrtf(dx * dx + dy * dy + dz * dz);
    const float inv_dz = 1.0f / dz;               // |dz| = 2*half_extent > 0
    const float step = vs2 * len * fabsf(inv_dz); // vs2 * len / |dz|

    float acc_total = 0.0f;

    for (int k = 0; k < n2; ++k) {
        const float zc = lo2 + ((float)k + 0.5f) * vs2;
        const float t  = (zc - p1z) * inv_dz;
        const float cx = fmaf(t, dx, p1x);
        const float cy = fmaf(t, dy, p1y);
        const float fx = (cx - lo0) * inv_vs0 - 0.5f;
        const float fy = (cy - lo1) * inv_vs1 - 0.5f;
        const int ix = (int)rintf(fx);  // half-to-even, matches jnp.round
        const int iy = (int)rintf(fy);
        const int kbase = k * s2;

        float acc = 0.0f;
#pragma unroll
        for (int o0 = -2; o0 <= 2; ++o0) {
            const int jx = ix + o0;
            if (jx < 0 || jx >= n0) continue;
            const float ddx  = (float)jx - fx;
            const float ddx2 = ddx * ddx;
            const int xbase  = jx * s0 + kbase;
#pragma unroll
            for (int o1 = -2; o1 <= 2; ++o1) {
                const int jy = iy + o1;
                if (jy < 0 || jy >= n1) continue;
                const float ddy = (float)jy - fy;
                const float d2  = fmaf(ddy, ddy, ddx2);
                if (d2 < KW2_F) {  // w > 0 iff dist < kernel_width
                    float w = fmaf(-sqrtf(d2), INV_KW_F, 1.0f);
                    w = fmaxf(w, 0.0f);
                    acc = fmaf(w, img[xbase + jy * s1], acc);
                }
            }
        }
        acc_total += acc;
    }

    out[i] = acc_total * step;
}

extern "C" void kernel_launch(void* const* d_in, const int* in_sizes, int n_in,
                              void* d_out, int out_size, void* d_ws, size_t ws_size,
                              hipStream_t stream)
{
    const float* img    = (const float*)d_in[0];
    const int*   grid   = (const int*)  d_in[1];
    const float* center = (const float*)d_in[2];
    const float* size   = (const float*)d_in[3];
    const float* xlors  = (const float*)d_in[4];
    const float* ylors  = (const float*)d_in[5];
    const float* zlors  = (const float*)d_in[6];
    float* out = (float*)d_out;

    const int nx = in_sizes[4] / 6;
    const int ny = in_sizes[5] / 6;
    const int nz = in_sizes[6] / 6;

    const int B = 256;

    // px: perm (2,0,1)  — img[jy, k, jx]
    tor_kernel<<<(nx + B - 1) / B, B, 0, stream>>>(
        img, grid, center, size, xlors, out, nx, 2, 0, 1);
    // py: perm (1,0,2)  — img[jy, jx, k]
    tor_kernel<<<(ny + B - 1) / B, B, 0, stream>>>(
        img, grid, center, size, ylors, out + nx, ny, 1, 0, 2);
    // pz: identity      — img[jx, jy, k]
    tor_kernel<<<(nz + B - 1) / B, B, 0, stream>>>(
        img, grid, center, size, zlors, out + nx + ny, nz, 0, 1, 2);
}